// Round 14
// baseline (128.289 us; speedup 1.0000x reference)
//
#include <hip/hip_runtime.h>

#define NN 10000
#define NE 640000
#define DIN 128
#define DOUT 256
#define BN_EPS 1e-5f
#define MPAD 10112    // 79 * 128
#define SLOTS_PN 160  // padded per-node list
#define NBKT 79       // coarse buckets of 128 nodes
#define NSB 256       // pass-A sort blocks
#define EPB 2500      // edges per sort block (256*2500 = 640000)

typedef __bf16 bf16x8 __attribute__((ext_vector_type(8)));
typedef float f32x4 __attribute__((ext_vector_type(4)));
typedef float f32x2 __attribute__((ext_vector_type(2)));
typedef unsigned char uchar;

#define P0_N 384    // 256 sortA | 128 bn+cvt
#define P1_N 79     // sortB only (critical path)
#define AG_N 3397   // 2500 agg1 | 256 w1 | 640 w2 | 1 bias

struct MegaP {
    const float* x; const int* src; const int* tgt;
    const float *gamma, *beta, *Wl1, *bl1, *Wr1, *Wl2, *bl2, *Wr2, *Wsr, *bs;
    float* out;
    float* colpart; float* bias1; float* biasc;
    int* nodecnt; int* boff; uint* bsorted;
    ushort* csr; ushort* agg1b; ushort* cat2; ushort* wcat1; ushort* wcat2;
    uint* x8; uchar* h8;
};

__device__ __forceinline__ ushort f2bf(float f) {
    uint u = __float_as_uint(f);
    u += 0x7fffu + ((u >> 16) & 1u);
    return (ushort)(u >> 16);
}
__device__ __forceinline__ uint pk2bf(float a, float b) {
    return (uint)f2bf(a) | ((uint)f2bf(b) << 16);
}
__device__ __forceinline__ uint fp8pk4(float a, float b, float c, float d) {
    int u = __builtin_amdgcn_cvt_pk_fp8_f32(a, b, 0, false);
    u = __builtin_amdgcn_cvt_pk_fp8_f32(c, d, u, true);
    return (uint)u;
}
__device__ __forceinline__ void gload16(const void* g, void* l) {
    __builtin_amdgcn_global_load_lds((const __attribute__((address_space(1))) uint*)g,
                                     (__attribute__((address_space(3))) uint*)l, 16, 0, 0);
}

// ---- sortA: block-local counting sort of EPB edges by coarse bucket (tgt>>7) ----
__device__ __forceinline__ void ph_sortA(char* smem, int vb, int tid,
                                         const int* __restrict__ src, const int* __restrict__ tgt,
                                         uint* __restrict__ bsorted, int* __restrict__ boff) {
    uint* bufIn  = (uint*)smem;              // 10000 B
    uint* bufOut = (uint*)(smem + 10000);    // 10000 B
    int*  h      = (int*)(smem + 20000);     // 320 B
    int*  h2     = (int*)(smem + 20320);     // 8 B
    int e0 = vb * EPB;
    for (int i = tid; i < EPB; i += 256)
        bufIn[i] = ((uint)tgt[e0 + i] << 16) | (uint)src[e0 + i];
    if (tid <= NBKT) h[tid] = 0;
    __syncthreads();
    for (int i = tid; i < EPB; i += 256)
        atomicAdd(&h[bufIn[i] >> 23], 1);
    __syncthreads();
    if (tid < 128) {
        int v = (tid <= NBKT) ? h[tid] : 0;
        int xv = v;
#pragma unroll
        for (int o = 1; o < 64; o <<= 1) {
            int y = __shfl_up(xv, o, 64);
            if ((tid & 63) >= o) xv += y;
        }
        if ((tid & 63) == 63) h2[tid >> 6] = xv;
        __syncthreads();
        int excl = xv - v + ((tid >= 64) ? h2[0] : 0);
        if (tid <= NBKT) {
            h[tid] = excl;
            boff[vb * (NBKT + 1) + tid] = excl;
        }
    } else {
        __syncthreads();
    }
    __syncthreads();
    for (int i = tid; i < EPB; i += 256) {
        uint p = bufIn[i];
        int pos = atomicAdd(&h[p >> 23], 1);
        bufOut[pos] = p;
    }
    __syncthreads();
    const uint4* so = (const uint4*)bufOut;
    uint4* dst = (uint4*)&bsorted[(size_t)vb * EPB];
    for (int i = tid; i < EPB / 4; i += 256) dst[i] = so[i];
}

// ---- fused BN partial sums + x conversions, one pass over blocked rows ----
__device__ __forceinline__ void ph_bncvt(char* smem, int vb, int tid,
                                         const float* __restrict__ x, float* __restrict__ colpart,
                                         ushort* __restrict__ cat2, uint* __restrict__ x8) {
    float4* ls = (float4*)smem;
    float4* lq = (float4*)(smem + 4096);
    int lane = tid & 31;
    int rl   = tid >> 5;
    int r0 = vb * 79;
    const float4* x4 = (const float4*)x;
    float4 s = make_float4(0, 0, 0, 0);
    float4 q = make_float4(0, 0, 0, 0);
#pragma unroll
    for (int it = 0; it < 10; ++it) {
        int r = r0 + it * 8 + rl;
        if (it * 8 + rl < 79 && r < NN) {
            float4 v = x4[(size_t)r * 32 + lane];
            s.x += v.x; s.y += v.y; s.z += v.z; s.w += v.w;
            q.x += v.x * v.x; q.y += v.y * v.y; q.z += v.z * v.z; q.w += v.w * v.w;
            ushort4 o;
            o.x = f2bf(v.x);
            o.y = f2bf(v.y);
            o.z = f2bf(v.z);
            o.w = f2bf(v.w);
            *(ushort4*)&cat2[(size_t)r * 640 + 512 + lane * 4] = o;
            x8[r * 32 + lane] = fp8pk4(v.x, v.y, v.z, v.w);
        }
    }
    ls[rl * 32 + lane] = s;
    lq[rl * 32 + lane] = q;
    __syncthreads();
    if (rl == 0) {
        for (int i = 1; i < 8; ++i) {
            float4 a = ls[i * 32 + lane];
            s.x += a.x; s.y += a.y; s.z += a.z; s.w += a.w;
            float4 b = lq[i * 32 + lane];
            q.x += b.x; q.y += b.y; q.z += b.z; q.w += b.w;
        }
        ((float4*)&colpart[vb * 256])[lane] = s;
        ((float4*)&colpart[vb * 256 + 128])[lane] = q;
    }
}

__device__ __forceinline__ void ph_w2(int vb, int tid,
                                      const float* __restrict__ Wl2, const float* __restrict__ Wr2,
                                      const float* __restrict__ Wsr, ushort* __restrict__ wcat2) {
    int i = vb * 256 + tid;
    if (i < 65536) {
        int r = i >> 8, c = i & 255;
        wcat2[r * 640 + c] = f2bf(Wr2[i]);
    } else if (i < 131072) {
        int j = i - 65536; int r = j >> 8, c = j & 255;
        wcat2[r * 640 + 256 + c] = f2bf(Wl2[j]);
    } else {
        int j = i - 131072; int r = j >> 7, c = j & 127;
        wcat2[r * 640 + 512 + c] = f2bf(Wsr[j]);
    }
}

__device__ __forceinline__ void ph_sortB(char* smem, int vb, int tid,
                                         const uint* __restrict__ bsorted, const int* __restrict__ boff,
                                         ushort* __restrict__ csr, int* __restrict__ nodecnt) {
    ushort* pad = (ushort*)smem;
    int* cur = (int*)(smem + 40960);
    int k = vb;
    if (tid < 128) cur[tid] = 0;
    __syncthreads();
    int wave = tid >> 6, lane = tid & 63;
    for (int b = wave; b < NSB; b += 4) {
        int j0 = boff[b * (NBKT + 1) + k];
        int j1 = boff[b * (NBKT + 1) + k + 1];
        const uint* run = &bsorted[(size_t)b * EPB];
        for (int j = j0 + lane; j < j1; j += 64) {
            uint p = run[j];
            int l = (p >> 16) & 127;
            int pos = atomicAdd(&cur[l], 1);
            if (pos < SLOTS_PN) pad[l * SLOTS_PN + pos] = (ushort)(p & 0xFFFFu);
        }
    }
    __syncthreads();
    const uint4* ps = (const uint4*)pad;
    uint4* pd = (uint4*)&csr[(size_t)k * 128 * SLOTS_PN];
    for (int i = tid; i < 128 * SLOTS_PN / 8; i += 256) pd[i] = ps[i];
    if (tid < 128) {
        int n = k * 128 + tid;
        if (n < NN) nodecnt[n] = min(cur[tid], SLOTS_PN);
    }
}

__device__ __forceinline__ void ph_w1(char* smem, int vb, int tid,
                                      const float* __restrict__ colpart, const float* __restrict__ gamma,
                                      const float* __restrict__ Wl1, const float* __restrict__ Wr1,
                                      ushort* __restrict__ wcat1) {
    float* s_sc = (float*)smem;
    if (tid < DIN) {
        float s = 0.f, q = 0.f;
        for (int b = 0; b < 128; ++b) {
            s += colpart[b * 256 + tid];
            q += colpart[b * 256 + 128 + tid];
        }
        float mean = s * (1.0f / NN);
        float var  = q * (1.0f / NN) - mean * mean;
        s_sc[tid] = gamma[tid] * rsqrtf(var + BN_EPS);
    }
    __syncthreads();
    int i = vb * 256 + tid;
    if (i < 32768) {
        int r = i >> 7, c = i & 127;
        wcat1[r * 256 + c] = f2bf(Wr1[i] * s_sc[c]);
    } else {
        int j = i - 32768; int r = j >> 7, c = j & 127;
        wcat1[r * 256 + 128 + c] = f2bf(Wl1[j] * s_sc[c]);
    }
}

__device__ __forceinline__ void ph_bias(char* smem, int tid,
                                        const float* __restrict__ colpart, const float* __restrict__ gamma,
                                        const float* __restrict__ beta,
                                        const float* __restrict__ Wl1, const float* __restrict__ Wr1,
                                        const float* __restrict__ bl1, const float* __restrict__ bl2,
                                        const float* __restrict__ bs,
                                        float* __restrict__ bias1, float* __restrict__ biasc) {
    float* s_sh = (float*)smem;
    if (tid < DIN) {
        float s = 0.f, q = 0.f;
        for (int b = 0; b < 128; ++b) {
            s += colpart[b * 256 + tid];
            q += colpart[b * 256 + 128 + tid];
        }
        float mean = s * (1.0f / NN);
        float var  = q * (1.0f / NN) - mean * mean;
        float sc   = gamma[tid] * rsqrtf(var + BN_EPS);
        s_sh[tid]  = beta[tid] - mean * sc;
    }
    __syncthreads();
    int n = tid;
    float acc = bl1[n];
    for (int k = 0; k < DIN; ++k)
        acc += (Wr1[n * DIN + k] + Wl1[n * DIN + k]) * s_sh[k];
    bias1[n] = acc;
    biasc[n] = bl2[n] + bs[n];
}

// ---- per-node segment-mean gather (one wave, CHUNKS x SLOTS = 64 lanes), unroll 4 ----
template <int CHUNKS, int SLOTS>
__device__ __forceinline__ void agg_node(int node, int lane, const uchar* __restrict__ feat8,
                                         int ld16, const int* __restrict__ nodecnt,
                                         const ushort* __restrict__ csr,
                                         ushort* __restrict__ outp, int outoff8, int outld8) {
    int chunk = lane % CHUNKS;
    int slot  = lane / CHUNKS;
    int cnt = nodecnt[node];
    const ushort* lst = &csr[(size_t)node * SLOTS_PN];
    const uint4* fp = (const uint4*)feat8;
    float acc[16];
#pragma unroll
    for (int k = 0; k < 16; ++k) acc[k] = 0.f;

#define ACC16(vv)                                                              \
    {                                                                          \
        f32x2 p;                                                               \
        p = __builtin_amdgcn_cvt_pk_f32_fp8((int)vv.x, false); acc[0] += p[0];  acc[1] += p[1];  \
        p = __builtin_amdgcn_cvt_pk_f32_fp8((int)vv.x, true);  acc[2] += p[0];  acc[3] += p[1];  \
        p = __builtin_amdgcn_cvt_pk_f32_fp8((int)vv.y, false); acc[4] += p[0];  acc[5] += p[1];  \
        p = __builtin_amdgcn_cvt_pk_f32_fp8((int)vv.y, true);  acc[6] += p[0];  acc[7] += p[1];  \
        p = __builtin_amdgcn_cvt_pk_f32_fp8((int)vv.z, false); acc[8] += p[0];  acc[9] += p[1];  \
        p = __builtin_amdgcn_cvt_pk_f32_fp8((int)vv.z, true);  acc[10] += p[0]; acc[11] += p[1]; \
        p = __builtin_amdgcn_cvt_pk_f32_fp8((int)vv.w, false); acc[12] += p[0]; acc[13] += p[1]; \
        p = __builtin_amdgcn_cvt_pk_f32_fp8((int)vv.w, true);  acc[14] += p[0]; acc[15] += p[1]; \
    }

    int j = slot;
    for (; j + 3 * SLOTS < cnt; j += 4 * SLOTS) {
        int a = lst[j], b = lst[j + SLOTS], c = lst[j + 2 * SLOTS], d = lst[j + 3 * SLOTS];
        uint4 va = fp[(size_t)a * ld16 + chunk];
        uint4 vb4 = fp[(size_t)b * ld16 + chunk];
        uint4 vc = fp[(size_t)c * ld16 + chunk];
        uint4 vd = fp[(size_t)d * ld16 + chunk];
        ACC16(va);
        ACC16(vb4);
        ACC16(vc);
        ACC16(vd);
    }
    for (; j < cnt; j += SLOTS) {
        int a = lst[j];
        uint4 va = fp[(size_t)a * ld16 + chunk];
        ACC16(va);
    }
#undef ACC16
#pragma unroll
    for (int m = CHUNKS; m < 64; m <<= 1)
#pragma unroll
        for (int k = 0; k < 16; ++k) acc[k] += __shfl_xor(acc[k], m, 64);
    if (slot == 0) {
        float inv = 1.0f / (float)(cnt > 1 ? cnt : 1);
        uint4 o0, o1;
        o0.x = pk2bf(acc[0] * inv, acc[1] * inv);
        o0.y = pk2bf(acc[2] * inv, acc[3] * inv);
        o0.z = pk2bf(acc[4] * inv, acc[5] * inv);
        o0.w = pk2bf(acc[6] * inv, acc[7] * inv);
        o1.x = pk2bf(acc[8] * inv, acc[9] * inv);
        o1.y = pk2bf(acc[10] * inv, acc[11] * inv);
        o1.z = pk2bf(acc[12] * inv, acc[13] * inv);
        o1.w = pk2bf(acc[14] * inv, acc[15] * inv);
        uint4* op = (uint4*)outp;
        op[(size_t)node * outld8 + outoff8 + chunk * 2]     = o0;
        op[(size_t)node * outld8 + outoff8 + chunk * 2 + 1] = o1;
    }
}

// ---- 128x128 MFMA GEMM, optional dual-source A (kt<2 from A, kt>=2 from A2) ----
template <int K, bool RELU, bool OUTF32, bool OUTF8, bool DUAL>
__device__ __forceinline__ void mm128(char* smem, int bx, int by, int tid,
                                      const ushort* __restrict__ A, int lda,
                                      const ushort* __restrict__ A2, int lda2,
                                      const ushort* __restrict__ W,
                                      const float* __restrict__ bias, float* __restrict__ outf,
                                      ushort* __restrict__ outb, int outld,
                                      uchar* __restrict__ out8) {
    ushort* As = (ushort*)smem;            // 128 x 64 = 16 KB
    ushort* Bs = (ushort*)(smem + 16384);  // 128 x 64 = 16 KB
    const int wid = tid >> 6;
    const int lane = tid & 63;
    const int wm = wid >> 1, wn = wid & 1;
    const int m0 = bx * 128;
    const int n0 = by * 128;

    const int srow = lane >> 3;
    const int schunk = (lane & 7) ^ srow;
    const int fr = lane & 15;
    const int kg = lane >> 4;
    const int swz = (fr & 7) * 8;
    const int kgo = kg * 8;

    f32x4 acc[4][4];
#pragma unroll
    for (int i = 0; i < 4; ++i)
#pragma unroll
        for (int j = 0; j < 4; ++j) acc[i][j] = (f32x4){0.f, 0.f, 0.f, 0.f};

#pragma unroll
    for (int kt = 0; kt < K / 64; ++kt) {
        const ushort* Ab = (DUAL && kt >= 2) ? A2 : A;
        const int ldb = (DUAL && kt >= 2) ? lda2 : lda;
        const int kto = (DUAL && kt >= 2) ? kt - 2 : kt;
#pragma unroll
        for (int i = 0; i < 4; ++i) {
            int rb = i * 32 + wid * 8;
            int r = rb + srow;
            gload16(&Ab[(size_t)(m0 + r) * ldb + kto * 64 + schunk * 8], &As[rb * 64]);
            gload16(&W[(size_t)(n0 + r) * K + kt * 64 + schunk * 8], &Bs[rb * 64]);
        }
        __syncthreads();
#pragma unroll
        for (int ks = 0; ks < 2; ++ks) {
            bf16x8 a[4], b[4];
            int koff = ks * 32 + kgo;
#pragma unroll
            for (int f = 0; f < 4; ++f) {
                a[f] = *(const bf16x8*)&As[(wm * 64 + f * 16 + fr) * 64 + (koff ^ swz)];
                b[f] = *(const bf16x8*)&Bs[(wn * 64 + f * 16 + fr) * 64 + (koff ^ swz)];
            }
#pragma unroll
            for (int i = 0; i < 4; ++i)
#pragma unroll
                for (int j = 0; j < 4; ++j)
                    acc[i][j] = __builtin_amdgcn_mfma_f32_16x16x32_bf16(a[i], b[j], acc[i][j], 0, 0, 0);
        }
        __syncthreads();
    }

#pragma unroll
    for (int j = 0; j < 4; ++j) {
        int n = n0 + wn * 64 + j * 16 + fr;
        float bv = bias[n];
#pragma unroll
        for (int i = 0; i < 4; ++i) {
#pragma unroll
            for (int r = 0; r < 4; ++r) {
                int m = m0 + wm * 64 + i * 16 + kg * 4 + r;
                if (m < NN) {
                    float v = acc[i][j][r] + bv;
                    if (RELU) v = fmaxf(v, 0.f);
                    if (OUTF32) outf[(size_t)m * outld + n] = v;
                    else        outb[(size_t)m * outld + n] = f2bf(v);
                    if (OUTF8)
                        out8[(size_t)m * DOUT + n] =
                            (uchar)((uint)__builtin_amdgcn_cvt_pk_fp8_f32(v, v, 0, false) & 0xffu);
                }
            }
        }
    }
}

// ---------------- kernels ----------------
__global__ __launch_bounds__(256) void k_p0(MegaP P) {
    __shared__ __align__(16) char smem[20352];
    int vb = blockIdx.x, tid = threadIdx.x;
    if (vb < NSB) ph_sortA(smem, vb, tid, P.src, P.tgt, P.bsorted, P.boff);
    else ph_bncvt(smem, vb - NSB, tid, P.x, P.colpart, P.cat2, P.x8);
}

__global__ __launch_bounds__(256) void k_p1(MegaP P) {
    __shared__ __align__(16) char smem[41472];
    ph_sortB(smem, blockIdx.x, threadIdx.x, P.bsorted, P.boff, P.csr, P.nodecnt);
}

// agg1 | w1 | w2 | bias  (w-prep overlaps latency-bound gathers)
__global__ __launch_bounds__(256) void k_agg1(MegaP P) {
    __shared__ __align__(16) char smem[512];
    int vb = blockIdx.x, tid = threadIdx.x;
    if (vb < 2500) {
        int node = vb * 4 + (tid >> 6);
        agg_node<8, 8>(node, tid & 63, (const uchar*)P.x8, 8, P.nodecnt, P.csr,
                       P.agg1b, 0, 16);
    } else if (vb < 2756) {
        ph_w1(smem, vb - 2500, tid, P.colpart, P.gamma, P.Wl1, P.Wr1, P.wcat1);
    } else if (vb < 3396) {
        ph_w2(vb - 2756, tid, P.Wl2, P.Wr2, P.Wsr, P.wcat2);
    } else {
        ph_bias(smem, tid, P.colpart, P.gamma, P.beta, P.Wl1, P.Wr1, P.bl1, P.bl2, P.bs,
                P.bias1, P.biasc);
    }
}

__global__ __launch_bounds__(256) void k_mm1(MegaP P) {
    __shared__ __align__(16) char smem[32768];
    // A: kt 0..1 = x (cat2 cols 512:640, lda 640); kt 2..3 = agg1b (lda 128)
    mm128<256, true, false, true, true>(smem, blockIdx.x, blockIdx.y, threadIdx.x,
                                        P.cat2 + 512, 640, P.agg1b, 128, P.wcat1,
                                        P.bias1, nullptr, P.cat2, 640, P.h8);
}

__global__ __launch_bounds__(256) void k_agg2(MegaP P) {
    int node = blockIdx.x * 4 + (threadIdx.x >> 6);
    agg_node<16, 4>(node, threadIdx.x & 63, P.h8, 16, P.nodecnt, P.csr, P.cat2, 32, 80);
}

__global__ __launch_bounds__(256) void k_mm2(MegaP P) {
    __shared__ __align__(16) char smem[32768];
    mm128<640, false, true, false, false>(smem, blockIdx.x, blockIdx.y, threadIdx.x,
                                          P.cat2, 640, nullptr, 0, P.wcat2,
                                          P.biasc, P.out, nullptr, 256, nullptr);
}

extern "C" void kernel_launch(void* const* d_in, const int* in_sizes, int n_in,
                              void* d_out, int out_size, void* d_ws, size_t ws_size,
                              hipStream_t stream) {
    const float* x  = (const float*)d_in[0];
    const int*   ei = (const int*)d_in[1];

    char* base = (char*)d_ws;
    size_t off = 0;
    auto alloc = [&](size_t bytes) -> void* {
        void* p = base + off;
        off += (bytes + 255) & ~(size_t)255;
        return p;
    };

    MegaP P;
    P.x = x; P.src = ei; P.tgt = ei + NE;
    P.gamma = (const float*)d_in[2];
    P.beta  = (const float*)d_in[3];
    P.Wl1   = (const float*)d_in[4];
    P.bl1   = (const float*)d_in[5];
    P.Wr1   = (const float*)d_in[6];
    P.Wl2   = (const float*)d_in[7];
    P.bl2   = (const float*)d_in[8];
    P.Wr2   = (const float*)d_in[9];
    P.Wsr   = (const float*)d_in[10];
    P.bs    = (const float*)d_in[11];
    P.out   = (float*)d_out;

    P.colpart = (float*)alloc(128 * 256 * sizeof(float));
    P.bias1   = (float*)alloc(DOUT * sizeof(float));
    P.biasc   = (float*)alloc(DOUT * sizeof(float));
    P.nodecnt = (int*)alloc(NN * sizeof(int));
    P.boff    = (int*)alloc((size_t)NSB * (NBKT + 1) * sizeof(int));
    P.bsorted = (uint*)alloc((size_t)NE * sizeof(uint));
    P.csr     = (ushort*)alloc((size_t)MPAD * SLOTS_PN * sizeof(ushort));
    P.agg1b   = (ushort*)alloc((size_t)MPAD * 128 * sizeof(ushort));
    P.cat2    = (ushort*)alloc((size_t)MPAD * 640 * sizeof(ushort));
    P.wcat1   = (ushort*)alloc(256 * 256 * sizeof(ushort));
    P.wcat2   = (ushort*)alloc(256 * 640 * sizeof(ushort));
    P.x8      = (uint*)alloc((size_t)MPAD * 128);
    P.h8      = (uchar*)alloc((size_t)MPAD * 256);

    k_p0<<<P0_N, 256, 0, stream>>>(P);
    k_p1<<<P1_N, 256, 0, stream>>>(P);
    k_agg1<<<AG_N, 256, 0, stream>>>(P);
    dim3 ggrid(MPAD / 128, 2);
    k_mm1<<<ggrid, 256, 0, stream>>>(P);
    k_agg2<<<NN / 4, 256, 0, stream>>>(P);
    k_mm2<<<ggrid, 256, 0, stream>>>(P);
}

// Round 15
// 98.107 us; speedup vs baseline: 1.3076x; 1.3076x over previous
//
#include <hip/hip_runtime.h>

#define NN 10000
#define NE 640000
#define DIN 128
#define DOUT 256
#define BN_EPS 1e-5f
#define MPAD 10112    // 79 * 128
#define SLOTS_PN 160  // padded per-node list
#define NBKT 79       // coarse buckets of 128 nodes
#define NSB 128       // pass-A sort blocks
#define EPB 5000      // edges per sort block (128*5000 = 640000)

typedef __bf16 bf16x8 __attribute__((ext_vector_type(8)));
typedef float f32x4 __attribute__((ext_vector_type(4)));
typedef float f32x2 __attribute__((ext_vector_type(2)));
typedef unsigned char uchar;

#define P0_N 896    // 128 sortA | 128 bn+cvt | 640 w2
#define P1_N 336    // 79 sortB | 256 w1 | 1 bias

struct MegaP {
    const float* x; const int* src; const int* tgt;
    const float *gamma, *beta, *Wl1, *bl1, *Wr1, *Wl2, *bl2, *Wr2, *Wsr, *bs;
    float* out;
    float* colpart; float* bias1; float* biasc;
    int* nodecnt; int* boff; uint* bsorted;
    ushort* csr; ushort* agg1b; ushort* cat2; ushort* wcat1; ushort* wcat2;
    uint* x8; uchar* h8;
};

__device__ __forceinline__ ushort f2bf(float f) {
    uint u = __float_as_uint(f);
    u += 0x7fffu + ((u >> 16) & 1u);
    return (ushort)(u >> 16);
}
__device__ __forceinline__ uint pk2bf(float a, float b) {
    return (uint)f2bf(a) | ((uint)f2bf(b) << 16);
}
__device__ __forceinline__ uint fp8pk4(float a, float b, float c, float d) {
    int u = __builtin_amdgcn_cvt_pk_fp8_f32(a, b, 0, false);
    u = __builtin_amdgcn_cvt_pk_fp8_f32(c, d, u, true);
    return (uint)u;
}
__device__ __forceinline__ void gload16(const void* g, void* l) {
    __builtin_amdgcn_global_load_lds((const __attribute__((address_space(1))) uint*)g,
                                     (__attribute__((address_space(3))) uint*)l, 16, 0, 0);
}

// ---- sortA: block-local counting sort of EPB edges by coarse bucket (tgt>>7) ----
__device__ __forceinline__ void ph_sortA(char* smem, int vb, int tid,
                                         const int* __restrict__ src, const int* __restrict__ tgt,
                                         uint* __restrict__ bsorted, int* __restrict__ boff) {
    uint* bufIn  = (uint*)smem;              // 20000 B
    uint* bufOut = (uint*)(smem + 20000);    // 20000 B
    int*  h      = (int*)(smem + 40000);     // 320 B
    int*  h2     = (int*)(smem + 40320);     // 8 B
    int e0 = vb * EPB;
    for (int i = tid; i < EPB; i += 256)
        bufIn[i] = ((uint)tgt[e0 + i] << 16) | (uint)src[e0 + i];
    if (tid <= NBKT) h[tid] = 0;
    __syncthreads();
    for (int i = tid; i < EPB; i += 256)
        atomicAdd(&h[bufIn[i] >> 23], 1);
    __syncthreads();
    if (tid < 128) {
        int v = (tid <= NBKT) ? h[tid] : 0;
        int xv = v;
#pragma unroll
        for (int o = 1; o < 64; o <<= 1) {
            int y = __shfl_up(xv, o, 64);
            if ((tid & 63) >= o) xv += y;
        }
        if ((tid & 63) == 63) h2[tid >> 6] = xv;
        __syncthreads();
        int excl = xv - v + ((tid >= 64) ? h2[0] : 0);
        if (tid <= NBKT) {
            h[tid] = excl;
            boff[vb * (NBKT + 1) + tid] = excl;
        }
    } else {
        __syncthreads();
    }
    __syncthreads();
    for (int i = tid; i < EPB; i += 256) {
        uint p = bufIn[i];
        int pos = atomicAdd(&h[p >> 23], 1);
        bufOut[pos] = p;
    }
    __syncthreads();
    const uint4* so = (const uint4*)bufOut;
    uint4* dst = (uint4*)&bsorted[(size_t)vb * EPB];
    for (int i = tid; i < EPB / 4; i += 256) dst[i] = so[i];
}

// ---- fused BN partial sums + x conversions, one pass over blocked rows ----
__device__ __forceinline__ void ph_bncvt(char* smem, int vb, int tid,
                                         const float* __restrict__ x, float* __restrict__ colpart,
                                         ushort* __restrict__ cat2, uint* __restrict__ x8) {
    float4* ls = (float4*)smem;
    float4* lq = (float4*)(smem + 4096);
    int lane = tid & 31;
    int rl   = tid >> 5;
    int r0 = vb * 79;
    const float4* x4 = (const float4*)x;
    float4 s = make_float4(0, 0, 0, 0);
    float4 q = make_float4(0, 0, 0, 0);
#pragma unroll
    for (int it = 0; it < 10; ++it) {
        int r = r0 + it * 8 + rl;
        if (it * 8 + rl < 79 && r < NN) {
            float4 v = x4[(size_t)r * 32 + lane];
            s.x += v.x; s.y += v.y; s.z += v.z; s.w += v.w;
            q.x += v.x * v.x; q.y += v.y * v.y; q.z += v.z * v.z; q.w += v.w * v.w;
            ushort4 o;
            o.x = f2bf(v.x);
            o.y = f2bf(v.y);
            o.z = f2bf(v.z);
            o.w = f2bf(v.w);
            *(ushort4*)&cat2[(size_t)r * 640 + 512 + lane * 4] = o;
            x8[r * 32 + lane] = fp8pk4(v.x, v.y, v.z, v.w);
        }
    }
    ls[rl * 32 + lane] = s;
    lq[rl * 32 + lane] = q;
    __syncthreads();
    if (rl == 0) {
        for (int i = 1; i < 8; ++i) {
            float4 a = ls[i * 32 + lane];
            s.x += a.x; s.y += a.y; s.z += a.z; s.w += a.w;
            float4 b = lq[i * 32 + lane];
            q.x += b.x; q.y += b.y; q.z += b.z; q.w += b.w;
        }
        ((float4*)&colpart[vb * 256])[lane] = s;
        ((float4*)&colpart[vb * 256 + 128])[lane] = q;
    }
}

__device__ __forceinline__ void ph_w2(int vb, int tid,
                                      const float* __restrict__ Wl2, const float* __restrict__ Wr2,
                                      const float* __restrict__ Wsr, ushort* __restrict__ wcat2) {
    int i = vb * 256 + tid;
    if (i < 65536) {
        int r = i >> 8, c = i & 255;
        wcat2[r * 640 + c] = f2bf(Wr2[i]);
    } else if (i < 131072) {
        int j = i - 65536; int r = j >> 8, c = j & 255;
        wcat2[r * 640 + 256 + c] = f2bf(Wl2[j]);
    } else {
        int j = i - 131072; int r = j >> 7, c = j & 127;
        wcat2[r * 640 + 512 + c] = f2bf(Wsr[j]);
    }
}

// ---- sortB: merge 128 runs -> padded per-node lists; boff prefetched to LDS ----
__device__ __forceinline__ void ph_sortB(char* smem, int vb, int tid,
                                         const uint* __restrict__ bsorted, const int* __restrict__ boff,
                                         ushort* __restrict__ csr, int* __restrict__ nodecnt) {
    ushort* pad = (ushort*)smem;              // 40960 B
    int* cur = (int*)(smem + 40960);          // 512 B
    int* jj  = (int*)(smem + 41472);          // 1024 B: j0,j1 per run
    int k = vb;
    if (tid < 128) cur[tid] = 0;
    // one parallel round of boff loads instead of 32 serial per-wave loads
    jj[tid] = boff[(tid >> 1) * (NBKT + 1) + k + (tid & 1)];
    __syncthreads();
    int wave = tid >> 6, lane = tid & 63;
#pragma unroll 2
    for (int b = wave; b < NSB; b += 4) {
        int j0 = jj[2 * b], j1 = jj[2 * b + 1];
        const uint* run = &bsorted[(size_t)b * EPB];
        for (int j = j0 + lane; j < j1; j += 64) {
            uint p = run[j];
            int l = (p >> 16) & 127;
            int pos = atomicAdd(&cur[l], 1);
            if (pos < SLOTS_PN) pad[l * SLOTS_PN + pos] = (ushort)(p & 0xFFFFu);
        }
    }
    __syncthreads();
    const uint4* ps = (const uint4*)pad;
    uint4* pd = (uint4*)&csr[(size_t)k * 128 * SLOTS_PN];
    for (int i = tid; i < 128 * SLOTS_PN / 8; i += 256) pd[i] = ps[i];
    if (tid < 128) {
        int n = k * 128 + tid;
        if (n < NN) nodecnt[n] = min(cur[tid], SLOTS_PN);
    }
}

__device__ __forceinline__ void ph_w1(char* smem, int vb, int tid,
                                      const float* __restrict__ colpart, const float* __restrict__ gamma,
                                      const float* __restrict__ Wl1, const float* __restrict__ Wr1,
                                      ushort* __restrict__ wcat1) {
    float* s_sc = (float*)smem;
    if (tid < DIN) {
        float s = 0.f, q = 0.f;
        for (int b = 0; b < 128; ++b) {
            s += colpart[b * 256 + tid];
            q += colpart[b * 256 + 128 + tid];
        }
        float mean = s * (1.0f / NN);
        float var  = q * (1.0f / NN) - mean * mean;
        s_sc[tid] = gamma[tid] * rsqrtf(var + BN_EPS);
    }
    __syncthreads();
    int i = vb * 256 + tid;
    if (i < 32768) {
        int r = i >> 7, c = i & 127;
        wcat1[r * 256 + c] = f2bf(Wr1[i] * s_sc[c]);
    } else {
        int j = i - 32768; int r = j >> 7, c = j & 127;
        wcat1[r * 256 + 128 + c] = f2bf(Wl1[j] * s_sc[c]);
    }
}

__device__ __forceinline__ void ph_bias(char* smem, int tid,
                                        const float* __restrict__ colpart, const float* __restrict__ gamma,
                                        const float* __restrict__ beta,
                                        const float* __restrict__ Wl1, const float* __restrict__ Wr1,
                                        const float* __restrict__ bl1, const float* __restrict__ bl2,
                                        const float* __restrict__ bs,
                                        float* __restrict__ bias1, float* __restrict__ biasc) {
    float* s_sh = (float*)smem;
    if (tid < DIN) {
        float s = 0.f, q = 0.f;
        for (int b = 0; b < 128; ++b) {
            s += colpart[b * 256 + tid];
            q += colpart[b * 256 + 128 + tid];
        }
        float mean = s * (1.0f / NN);
        float var  = q * (1.0f / NN) - mean * mean;
        float sc   = gamma[tid] * rsqrtf(var + BN_EPS);
        s_sh[tid]  = beta[tid] - mean * sc;
    }
    __syncthreads();
    int n = tid;
    float acc = bl1[n];
    for (int k = 0; k < DIN; ++k)
        acc += (Wr1[n * DIN + k] + Wl1[n * DIN + k]) * s_sh[k];
    bias1[n] = acc;
    biasc[n] = bl2[n] + bs[n];
}

// ---- per-node segment-mean gather (one wave, CHUNKS x SLOTS = 64 lanes), unroll 4 ----
template <int CHUNKS, int SLOTS>
__device__ __forceinline__ void agg_node(int node, int lane, const uchar* __restrict__ feat8,
                                         int ld16, const int* __restrict__ nodecnt,
                                         const ushort* __restrict__ csr,
                                         ushort* __restrict__ outp, int outoff8, int outld8) {
    int chunk = lane % CHUNKS;
    int slot  = lane / CHUNKS;
    int cnt = nodecnt[node];
    const ushort* lst = &csr[(size_t)node * SLOTS_PN];
    const uint4* fp = (const uint4*)feat8;
    float acc[16];
#pragma unroll
    for (int k = 0; k < 16; ++k) acc[k] = 0.f;

#define ACC16(vv)                                                              \
    {                                                                          \
        f32x2 p;                                                               \
        p = __builtin_amdgcn_cvt_pk_f32_fp8((int)vv.x, false); acc[0] += p[0];  acc[1] += p[1];  \
        p = __builtin_amdgcn_cvt_pk_f32_fp8((int)vv.x, true);  acc[2] += p[0];  acc[3] += p[1];  \
        p = __builtin_amdgcn_cvt_pk_f32_fp8((int)vv.y, false); acc[4] += p[0];  acc[5] += p[1];  \
        p = __builtin_amdgcn_cvt_pk_f32_fp8((int)vv.y, true);  acc[6] += p[0];  acc[7] += p[1];  \
        p = __builtin_amdgcn_cvt_pk_f32_fp8((int)vv.z, false); acc[8] += p[0];  acc[9] += p[1];  \
        p = __builtin_amdgcn_cvt_pk_f32_fp8((int)vv.z, true);  acc[10] += p[0]; acc[11] += p[1]; \
        p = __builtin_amdgcn_cvt_pk_f32_fp8((int)vv.w, false); acc[12] += p[0]; acc[13] += p[1]; \
        p = __builtin_amdgcn_cvt_pk_f32_fp8((int)vv.w, true);  acc[14] += p[0]; acc[15] += p[1]; \
    }

    int j = slot;
    for (; j + 3 * SLOTS < cnt; j += 4 * SLOTS) {
        int a = lst[j], b = lst[j + SLOTS], c = lst[j + 2 * SLOTS], d = lst[j + 3 * SLOTS];
        uint4 va = fp[(size_t)a * ld16 + chunk];
        uint4 vb4 = fp[(size_t)b * ld16 + chunk];
        uint4 vc = fp[(size_t)c * ld16 + chunk];
        uint4 vd = fp[(size_t)d * ld16 + chunk];
        ACC16(va);
        ACC16(vb4);
        ACC16(vc);
        ACC16(vd);
    }
    for (; j < cnt; j += SLOTS) {
        int a = lst[j];
        uint4 va = fp[(size_t)a * ld16 + chunk];
        ACC16(va);
    }
#undef ACC16
#pragma unroll
    for (int m = CHUNKS; m < 64; m <<= 1)
#pragma unroll
        for (int k = 0; k < 16; ++k) acc[k] += __shfl_xor(acc[k], m, 64);
    if (slot == 0) {
        float inv = 1.0f / (float)(cnt > 1 ? cnt : 1);
        uint4 o0, o1;
        o0.x = pk2bf(acc[0] * inv, acc[1] * inv);
        o0.y = pk2bf(acc[2] * inv, acc[3] * inv);
        o0.z = pk2bf(acc[4] * inv, acc[5] * inv);
        o0.w = pk2bf(acc[6] * inv, acc[7] * inv);
        o1.x = pk2bf(acc[8] * inv, acc[9] * inv);
        o1.y = pk2bf(acc[10] * inv, acc[11] * inv);
        o1.z = pk2bf(acc[12] * inv, acc[13] * inv);
        o1.w = pk2bf(acc[14] * inv, acc[15] * inv);
        uint4* op = (uint4*)outp;
        op[(size_t)node * outld8 + outoff8 + chunk * 2]     = o0;
        op[(size_t)node * outld8 + outoff8 + chunk * 2 + 1] = o1;
    }
}

// ---- 128x128 MFMA GEMM, optional dual-source A (kt<2 from A, kt>=2 from A2) ----
template <int K, bool RELU, bool OUTF32, bool OUTF8, bool DUAL>
__device__ __forceinline__ void mm128(char* smem, int bx, int by, int tid,
                                      const ushort* __restrict__ A, int lda,
                                      const ushort* __restrict__ A2, int lda2,
                                      const ushort* __restrict__ W,
                                      const float* __restrict__ bias, float* __restrict__ outf,
                                      ushort* __restrict__ outb, int outld,
                                      uchar* __restrict__ out8) {
    ushort* As = (ushort*)smem;            // 128 x 64 = 16 KB
    ushort* Bs = (ushort*)(smem + 16384);  // 128 x 64 = 16 KB
    const int wid = tid >> 6;
    const int lane = tid & 63;
    const int wm = wid >> 1, wn = wid & 1;
    const int m0 = bx * 128;
    const int n0 = by * 128;

    const int srow = lane >> 3;
    const int schunk = (lane & 7) ^ srow;
    const int fr = lane & 15;
    const int kg = lane >> 4;
    const int swz = (fr & 7) * 8;
    const int kgo = kg * 8;

    f32x4 acc[4][4];
#pragma unroll
    for (int i = 0; i < 4; ++i)
#pragma unroll
        for (int j = 0; j < 4; ++j) acc[i][j] = (f32x4){0.f, 0.f, 0.f, 0.f};

#pragma unroll
    for (int kt = 0; kt < K / 64; ++kt) {
        const ushort* Ab = (DUAL && kt >= 2) ? A2 : A;
        const int ldb = (DUAL && kt >= 2) ? lda2 : lda;
        const int kto = (DUAL && kt >= 2) ? kt - 2 : kt;
#pragma unroll
        for (int i = 0; i < 4; ++i) {
            int rb = i * 32 + wid * 8;
            int r = rb + srow;
            gload16(&Ab[(size_t)(m0 + r) * ldb + kto * 64 + schunk * 8], &As[rb * 64]);
            gload16(&W[(size_t)(n0 + r) * K + kt * 64 + schunk * 8], &Bs[rb * 64]);
        }
        __syncthreads();
#pragma unroll
        for (int ks = 0; ks < 2; ++ks) {
            bf16x8 a[4], b[4];
            int koff = ks * 32 + kgo;
#pragma unroll
            for (int f = 0; f < 4; ++f) {
                a[f] = *(const bf16x8*)&As[(wm * 64 + f * 16 + fr) * 64 + (koff ^ swz)];
                b[f] = *(const bf16x8*)&Bs[(wn * 64 + f * 16 + fr) * 64 + (koff ^ swz)];
            }
#pragma unroll
            for (int i = 0; i < 4; ++i)
#pragma unroll
                for (int j = 0; j < 4; ++j)
                    acc[i][j] = __builtin_amdgcn_mfma_f32_16x16x32_bf16(a[i], b[j], acc[i][j], 0, 0, 0);
        }
        __syncthreads();
    }

#pragma unroll
    for (int j = 0; j < 4; ++j) {
        int n = n0 + wn * 64 + j * 16 + fr;
        float bv = bias[n];
#pragma unroll
        for (int i = 0; i < 4; ++i) {
#pragma unroll
            for (int r = 0; r < 4; ++r) {
                int m = m0 + wm * 64 + i * 16 + kg * 4 + r;
                if (m < NN) {
                    float v = acc[i][j][r] + bv;
                    if (RELU) v = fmaxf(v, 0.f);
                    if (OUTF32) outf[(size_t)m * outld + n] = v;
                    else        outb[(size_t)m * outld + n] = f2bf(v);
                    if (OUTF8)
                        out8[(size_t)m * DOUT + n] =
                            (uchar)((uint)__builtin_amdgcn_cvt_pk_fp8_f32(v, v, 0, false) & 0xffu);
                }
            }
        }
    }
}

// ---------------- kernels ----------------
__global__ __launch_bounds__(256) void k_p0(MegaP P) {
    __shared__ __align__(16) char smem[40336];
    int vb = blockIdx.x, tid = threadIdx.x;
    if (vb < 128) ph_sortA(smem, vb, tid, P.src, P.tgt, P.bsorted, P.boff);
    else if (vb < 256) ph_bncvt(smem, vb - 128, tid, P.x, P.colpart, P.cat2, P.x8);
    else ph_w2(vb - 256, tid, P.Wl2, P.Wr2, P.Wsr, P.wcat2);
}

__global__ __launch_bounds__(256) void k_p1(MegaP P) {
    __shared__ __align__(16) char smem[42496];
    int vb = blockIdx.x, tid = threadIdx.x;
    if (vb < 79) ph_sortB(smem, vb, tid, P.bsorted, P.boff, P.csr, P.nodecnt);
    else if (vb < 335) ph_w1(smem, vb - 79, tid, P.colpart, P.gamma, P.Wl1, P.Wr1, P.wcat1);
    else ph_bias(smem, tid, P.colpart, P.gamma, P.beta, P.Wl1, P.Wr1, P.bl1, P.bl2, P.bs,
                 P.bias1, P.biasc);
}

__global__ __launch_bounds__(256) void k_agg1(MegaP P) {
    int node = blockIdx.x * 4 + (threadIdx.x >> 6);
    agg_node<8, 8>(node, threadIdx.x & 63, (const uchar*)P.x8, 8, P.nodecnt, P.csr,
                   P.agg1b, 0, 16);
}

__global__ __launch_bounds__(256) void k_mm1(MegaP P) {
    __shared__ __align__(16) char smem[32768];
    // A: kt 0..1 = x (cat2 cols 512:640, lda 640); kt 2..3 = agg1b (lda 128)
    mm128<256, true, false, true, true>(smem, blockIdx.x, blockIdx.y, threadIdx.x,
                                        P.cat2 + 512, 640, P.agg1b, 128, P.wcat1,
                                        P.bias1, nullptr, P.cat2, 640, P.h8);
}

__global__ __launch_bounds__(256) void k_agg2(MegaP P) {
    int node = blockIdx.x * 4 + (threadIdx.x >> 6);
    agg_node<16, 4>(node, threadIdx.x & 63, P.h8, 16, P.nodecnt, P.csr, P.cat2, 32, 80);
}

__global__ __launch_bounds__(256) void k_mm2(MegaP P) {
    __shared__ __align__(16) char smem[32768];
    mm128<640, false, true, false, false>(smem, blockIdx.x, blockIdx.y, threadIdx.x,
                                          P.cat2, 640, nullptr, 0, P.wcat2,
                                          P.biasc, P.out, nullptr, 256, nullptr);
}

extern "C" void kernel_launch(void* const* d_in, const int* in_sizes, int n_in,
                              void* d_out, int out_size, void* d_ws, size_t ws_size,
                              hipStream_t stream) {
    const float* x  = (const float*)d_in[0];
    const int*   ei = (const int*)d_in[1];

    char* base = (char*)d_ws;
    size_t off = 0;
    auto alloc = [&](size_t bytes) -> void* {
        void* p = base + off;
        off += (bytes + 255) & ~(size_t)255;
        return p;
    };

    MegaP P;
    P.x = x; P.src = ei; P.tgt = ei + NE;
    P.gamma = (const float*)d_in[2];
    P.beta  = (const float*)d_in[3];
    P.Wl1   = (const float*)d_in[4];
    P.bl1   = (const float*)d_in[5];
    P.Wr1   = (const float*)d_in[6];
    P.Wl2   = (const float*)d_in[7];
    P.bl2   = (const float*)d_in[8];
    P.Wr2   = (const float*)d_in[9];
    P.Wsr   = (const float*)d_in[10];
    P.bs    = (const float*)d_in[11];
    P.out   = (float*)d_out;

    P.colpart = (float*)alloc(128 * 256 * sizeof(float));
    P.bias1   = (float*)alloc(DOUT * sizeof(float));
    P.biasc   = (float*)alloc(DOUT * sizeof(float));
    P.nodecnt = (int*)alloc(NN * sizeof(int));
    P.boff    = (int*)alloc((size_t)NSB * (NBKT + 1) * sizeof(int));
    P.bsorted = (uint*)alloc((size_t)NE * sizeof(uint));
    P.csr     = (ushort*)alloc((size_t)MPAD * SLOTS_PN * sizeof(ushort));
    P.agg1b   = (ushort*)alloc((size_t)MPAD * 128 * sizeof(ushort));
    P.cat2    = (ushort*)alloc((size_t)MPAD * 640 * sizeof(ushort));
    P.wcat1   = (ushort*)alloc(256 * 256 * sizeof(ushort));
    P.wcat2   = (ushort*)alloc(256 * 640 * sizeof(ushort));
    P.x8      = (uint*)alloc((size_t)MPAD * 128);
    P.h8      = (uchar*)alloc((size_t)MPAD * 256);

    k_p0<<<P0_N, 256, 0, stream>>>(P);
    k_p1<<<P1_N, 256, 0, stream>>>(P);
    k_agg1<<<NN / 4, 256, 0, stream>>>(P);
    dim3 ggrid(MPAD / 128, 2);
    k_mm1<<<ggrid, 256, 0, stream>>>(P);
    k_agg2<<<NN / 4, 256, 0, stream>>>(P);
    k_mm2<<<ggrid, 256, 0, stream>>>(P);
}

// Round 16
// 94.352 us; speedup vs baseline: 1.3597x; 1.0398x over previous
//
#include <hip/hip_runtime.h>

#define NN 10000
#define NE 640000
#define DIN 128
#define DOUT 256
#define BN_EPS 1e-5f
#define MPAD 10112    // 79 * 128
#define SLOTS_PN 160  // padded per-node list
#define NBKT 79       // coarse buckets of 128 nodes
#define NSB 128       // pass-A sort blocks
#define EPB 5000      // edges per sort block (128*5000 = 640000)

typedef __bf16 bf16x8 __attribute__((ext_vector_type(8)));
typedef float f32x4 __attribute__((ext_vector_type(4)));
typedef float f32x2 __attribute__((ext_vector_type(2)));
typedef unsigned char uchar;

#define P0_N 896    // 128 sortA | 128 bn+cvt | 640 w2
#define P1_N 336    // 79 sortB | 256 w1 | 1 bias

struct MegaP {
    const float* x; const int* src; const int* tgt;
    const float *gamma, *beta, *Wl1, *bl1, *Wr1, *Wl2, *bl2, *Wr2, *Wsr, *bs;
    float* out;
    float* colpart; float* bias1; float* biasc;
    int* nodecnt; int* boff; uint* bsorted;
    ushort* csr; ushort* xcat; ushort* wcat1; ushort* wcat2;
    uint* x8; uchar* y8;
};

__device__ __forceinline__ ushort f2bf(float f) {
    uint u = __float_as_uint(f);
    u += 0x7fffu + ((u >> 16) & 1u);
    return (ushort)(u >> 16);
}
__device__ __forceinline__ uint pk2bf(float a, float b) {
    return (uint)f2bf(a) | ((uint)f2bf(b) << 16);
}
__device__ __forceinline__ uint fp8pk4(float a, float b, float c, float d) {
    int u = __builtin_amdgcn_cvt_pk_fp8_f32(a, b, 0, false);
    u = __builtin_amdgcn_cvt_pk_fp8_f32(c, d, u, true);
    return (uint)u;
}
__device__ __forceinline__ uchar fp81(float v) {
    return (uchar)((uint)__builtin_amdgcn_cvt_pk_fp8_f32(v, v, 0, false) & 0xffu);
}
__device__ __forceinline__ void gload16(const void* g, void* l) {
    __builtin_amdgcn_global_load_lds((const __attribute__((address_space(1))) uint*)g,
                                     (__attribute__((address_space(3))) uint*)l, 16, 0, 0);
}
// swizzled h1-tile address (ushort units): rows x 256 cols, 64-col K-tiles
__device__ __forceinline__ int h1addr(int row, int col) {
    return row * 256 + (col & ~63) + ((((col & 63) >> 3) ^ (row & 7)) << 3) + (col & 7);
}

// ---- sortA: block-local counting sort of EPB edges by coarse bucket (tgt>>7) ----
__device__ __forceinline__ void ph_sortA(char* smem, int vb, int tid,
                                         const int* __restrict__ src, const int* __restrict__ tgt,
                                         uint* __restrict__ bsorted, int* __restrict__ boff) {
    uint* bufIn  = (uint*)smem;
    uint* bufOut = (uint*)(smem + 20000);
    int*  h      = (int*)(smem + 40000);
    int*  h2     = (int*)(smem + 40320);
    int e0 = vb * EPB;
    for (int i = tid; i < EPB; i += 256)
        bufIn[i] = ((uint)tgt[e0 + i] << 16) | (uint)src[e0 + i];
    if (tid <= NBKT) h[tid] = 0;
    __syncthreads();
    for (int i = tid; i < EPB; i += 256)
        atomicAdd(&h[bufIn[i] >> 23], 1);
    __syncthreads();
    if (tid < 128) {
        int v = (tid <= NBKT) ? h[tid] : 0;
        int xv = v;
#pragma unroll
        for (int o = 1; o < 64; o <<= 1) {
            int y = __shfl_up(xv, o, 64);
            if ((tid & 63) >= o) xv += y;
        }
        if ((tid & 63) == 63) h2[tid >> 6] = xv;
        __syncthreads();
        int excl = xv - v + ((tid >= 64) ? h2[0] : 0);
        if (tid <= NBKT) {
            h[tid] = excl;
            boff[vb * (NBKT + 1) + tid] = excl;
        }
    } else {
        __syncthreads();
    }
    __syncthreads();
    for (int i = tid; i < EPB; i += 256) {
        uint p = bufIn[i];
        int pos = atomicAdd(&h[p >> 23], 1);
        bufOut[pos] = p;
    }
    __syncthreads();
    const uint4* so = (const uint4*)bufOut;
    uint4* dst = (uint4*)&bsorted[(size_t)vb * EPB];
    for (int i = tid; i < EPB / 4; i += 256) dst[i] = so[i];
}

// ---- fused BN partial sums + x conversions (xcat cols 0:128 bf16 + x8 fp8) ----
__device__ __forceinline__ void ph_bncvt(char* smem, int vb, int tid,
                                         const float* __restrict__ x, float* __restrict__ colpart,
                                         ushort* __restrict__ xcat, uint* __restrict__ x8) {
    float4* ls = (float4*)smem;
    float4* lq = (float4*)(smem + 4096);
    int lane = tid & 31;
    int rl   = tid >> 5;
    int r0 = vb * 79;
    const float4* x4 = (const float4*)x;
    float4 s = make_float4(0, 0, 0, 0);
    float4 q = make_float4(0, 0, 0, 0);
#pragma unroll
    for (int it = 0; it < 10; ++it) {
        int r = r0 + it * 8 + rl;
        if (it * 8 + rl < 79 && r < NN) {
            float4 v = x4[(size_t)r * 32 + lane];
            s.x += v.x; s.y += v.y; s.z += v.z; s.w += v.w;
            q.x += v.x * v.x; q.y += v.y * v.y; q.z += v.z * v.z; q.w += v.w * v.w;
            ushort4 o;
            o.x = f2bf(v.x);
            o.y = f2bf(v.y);
            o.z = f2bf(v.z);
            o.w = f2bf(v.w);
            *(ushort4*)&xcat[(size_t)r * 256 + lane * 4] = o;
            x8[r * 32 + lane] = fp8pk4(v.x, v.y, v.z, v.w);
        }
    }
    ls[rl * 32 + lane] = s;
    lq[rl * 32 + lane] = q;
    __syncthreads();
    if (rl == 0) {
        for (int i = 1; i < 8; ++i) {
            float4 a = ls[i * 32 + lane];
            s.x += a.x; s.y += a.y; s.z += a.z; s.w += a.w;
            float4 b = lq[i * 32 + lane];
            q.x += b.x; q.y += b.y; q.z += b.z; q.w += b.w;
        }
        ((float4*)&colpart[vb * 256])[lane] = s;
        ((float4*)&colpart[vb * 256 + 128])[lane] = q;
    }
}

__device__ __forceinline__ void ph_w2(int vb, int tid,
                                      const float* __restrict__ Wl2, const float* __restrict__ Wr2,
                                      const float* __restrict__ Wsr, ushort* __restrict__ wcat2) {
    int i = vb * 256 + tid;
    if (i < 65536) {
        int r = i >> 8, c = i & 255;
        wcat2[r * 640 + c] = f2bf(Wr2[i]);
    } else if (i < 131072) {
        int j = i - 65536; int r = j >> 8, c = j & 255;
        wcat2[r * 640 + 256 + c] = f2bf(Wl2[j]);
    } else {
        int j = i - 131072; int r = j >> 7, c = j & 127;
        wcat2[r * 640 + 512 + c] = f2bf(Wsr[j]);
    }
}

// ---- sortB: merge 128 runs -> padded per-node lists; boff prefetched to LDS ----
__device__ __forceinline__ void ph_sortB(char* smem, int vb, int tid,
                                         const uint* __restrict__ bsorted, const int* __restrict__ boff,
                                         ushort* __restrict__ csr, int* __restrict__ nodecnt) {
    ushort* pad = (ushort*)smem;
    int* cur = (int*)(smem + 40960);
    int* jj  = (int*)(smem + 41472);
    int k = vb;
    if (tid < 128) cur[tid] = 0;
    jj[tid] = boff[(tid >> 1) * (NBKT + 1) + k + (tid & 1)];
    __syncthreads();
    int wave = tid >> 6, lane = tid & 63;
#pragma unroll 2
    for (int b = wave; b < NSB; b += 4) {
        int j0 = jj[2 * b], j1 = jj[2 * b + 1];
        const uint* run = &bsorted[(size_t)b * EPB];
        for (int j = j0 + lane; j < j1; j += 64) {
            uint p = run[j];
            int l = (p >> 16) & 127;
            int pos = atomicAdd(&cur[l], 1);
            if (pos < SLOTS_PN) pad[l * SLOTS_PN + pos] = (ushort)(p & 0xFFFFu);
        }
    }
    __syncthreads();
    const uint4* ps = (const uint4*)pad;
    uint4* pd = (uint4*)&csr[(size_t)k * 128 * SLOTS_PN];
    for (int i = tid; i < 128 * SLOTS_PN / 8; i += 256) pd[i] = ps[i];
    if (tid < 128) {
        int n = k * 128 + tid;
        if (n < NN) nodecnt[n] = min(cur[tid], SLOTS_PN);
    }
}

__device__ __forceinline__ void ph_w1(char* smem, int vb, int tid,
                                      const float* __restrict__ colpart, const float* __restrict__ gamma,
                                      const float* __restrict__ Wl1, const float* __restrict__ Wr1,
                                      ushort* __restrict__ wcat1) {
    float* s_sc = (float*)smem;
    if (tid < DIN) {
        float s = 0.f, q = 0.f;
        for (int b = 0; b < 128; ++b) {
            s += colpart[b * 256 + tid];
            q += colpart[b * 256 + 128 + tid];
        }
        float mean = s * (1.0f / NN);
        float var  = q * (1.0f / NN) - mean * mean;
        s_sc[tid] = gamma[tid] * rsqrtf(var + BN_EPS);
    }
    __syncthreads();
    int i = vb * 256 + tid;
    if (i < 32768) {
        int r = i >> 7, c = i & 127;
        wcat1[r * 256 + c] = f2bf(Wr1[i] * s_sc[c]);
    } else {
        int j = i - 32768; int r = j >> 7, c = j & 127;
        wcat1[r * 256 + 128 + c] = f2bf(Wl1[j] * s_sc[c]);
    }
}

__device__ __forceinline__ void ph_bias(char* smem, int tid,
                                        const float* __restrict__ colpart, const float* __restrict__ gamma,
                                        const float* __restrict__ beta,
                                        const float* __restrict__ Wl1, const float* __restrict__ Wr1,
                                        const float* __restrict__ bl1, const float* __restrict__ bl2,
                                        const float* __restrict__ bs,
                                        float* __restrict__ bias1, float* __restrict__ biasc) {
    float* s_sh = (float*)smem;
    if (tid < DIN) {
        float s = 0.f, q = 0.f;
        for (int b = 0; b < 128; ++b) {
            s += colpart[b * 256 + tid];
            q += colpart[b * 256 + 128 + tid];
        }
        float mean = s * (1.0f / NN);
        float var  = q * (1.0f / NN) - mean * mean;
        float sc   = gamma[tid] * rsqrtf(var + BN_EPS);
        s_sh[tid]  = beta[tid] - mean * sc;
    }
    __syncthreads();
    int n = tid;
    float acc = bl1[n];
    for (int k = 0; k < DIN; ++k)
        acc += (Wr1[n * DIN + k] + Wl1[n * DIN + k]) * s_sh[k];
    bias1[n] = acc;
    biasc[n] = bl2[n] + bs[n];
}

// ---- fp8 gather core: accumulates 16 cols (chunk) over neighbor list ----
template <int CHUNKS, int SLOTS>
__device__ __forceinline__ void agg_core(int cnt, const ushort* __restrict__ lst,
                                         const uint4* __restrict__ fp, int ld16, int chunk,
                                         int slot, float* acc) {
#define ACC16(vv)                                                              \
    {                                                                          \
        f32x2 p;                                                               \
        p = __builtin_amdgcn_cvt_pk_f32_fp8((int)vv.x, false); acc[0] += p[0];  acc[1] += p[1];  \
        p = __builtin_amdgcn_cvt_pk_f32_fp8((int)vv.x, true);  acc[2] += p[0];  acc[3] += p[1];  \
        p = __builtin_amdgcn_cvt_pk_f32_fp8((int)vv.y, false); acc[4] += p[0];  acc[5] += p[1];  \
        p = __builtin_amdgcn_cvt_pk_f32_fp8((int)vv.y, true);  acc[6] += p[0];  acc[7] += p[1];  \
        p = __builtin_amdgcn_cvt_pk_f32_fp8((int)vv.z, false); acc[8] += p[0];  acc[9] += p[1];  \
        p = __builtin_amdgcn_cvt_pk_f32_fp8((int)vv.z, true);  acc[10] += p[0]; acc[11] += p[1]; \
        p = __builtin_amdgcn_cvt_pk_f32_fp8((int)vv.w, false); acc[12] += p[0]; acc[13] += p[1]; \
        p = __builtin_amdgcn_cvt_pk_f32_fp8((int)vv.w, true);  acc[14] += p[0]; acc[15] += p[1]; \
    }
    int j = slot;
    for (; j + 3 * SLOTS < cnt; j += 4 * SLOTS) {
        int a = lst[j], b = lst[j + SLOTS], c = lst[j + 2 * SLOTS], d = lst[j + 3 * SLOTS];
        uint4 va = fp[(size_t)a * ld16 + chunk];
        uint4 vb4 = fp[(size_t)b * ld16 + chunk];
        uint4 vc = fp[(size_t)c * ld16 + chunk];
        uint4 vd = fp[(size_t)d * ld16 + chunk];
        ACC16(va);
        ACC16(vb4);
        ACC16(vc);
        ACC16(vd);
    }
    for (; j < cnt; j += SLOTS) {
        int a = lst[j];
        uint4 va = fp[(size_t)a * ld16 + chunk];
        ACC16(va);
    }
#undef ACC16
#pragma unroll
    for (int m = CHUNKS; m < 64; m <<= 1)
#pragma unroll
        for (int k = 0; k < 16; ++k) acc[k] += __shfl_xor(acc[k], m, 64);
}

// ---- agg1: gather x8 -> xcat cols 128:256 (bf16) ----
__global__ __launch_bounds__(256) void k_agg1(MegaP P) {
    int node = blockIdx.x * 4 + (threadIdx.x >> 6);
    int lane = threadIdx.x & 63;
    int chunk = lane % 8, slot = lane / 8;
    int cnt = P.nodecnt[node];
    const ushort* lst = &P.csr[(size_t)node * SLOTS_PN];
    float acc[16];
#pragma unroll
    for (int k = 0; k < 16; ++k) acc[k] = 0.f;
    agg_core<8, 8>(cnt, lst, (const uint4*)P.x8, 8, chunk, slot, acc);
    if (slot == 0) {
        float inv = 1.0f / (float)(cnt > 1 ? cnt : 1);
        uint4 o0, o1;
        o0.x = pk2bf(acc[0] * inv, acc[1] * inv);
        o0.y = pk2bf(acc[2] * inv, acc[3] * inv);
        o0.z = pk2bf(acc[4] * inv, acc[5] * inv);
        o0.w = pk2bf(acc[6] * inv, acc[7] * inv);
        o1.x = pk2bf(acc[8] * inv, acc[9] * inv);
        o1.y = pk2bf(acc[10] * inv, acc[11] * inv);
        o1.z = pk2bf(acc[12] * inv, acc[13] * inv);
        o1.w = pk2bf(acc[14] * inv, acc[15] * inv);
        uint4* op = (uint4*)P.xcat;
        op[(size_t)node * 32 + 16 + chunk * 2]     = o0;
        op[(size_t)node * 32 + 16 + chunk * 2 + 1] = o1;
    }
}

// ---- agg2o: out += gather-mean(y8)  (f32 in-place) ----
__global__ __launch_bounds__(256) void k_agg2o(MegaP P) {
    int node = blockIdx.x * 4 + (threadIdx.x >> 6);
    int lane = threadIdx.x & 63;
    int chunk = lane % 16, slot = lane / 16;
    int cnt = P.nodecnt[node];
    const ushort* lst = &P.csr[(size_t)node * SLOTS_PN];
    float acc[16];
#pragma unroll
    for (int k = 0; k < 16; ++k) acc[k] = 0.f;
    agg_core<16, 4>(cnt, lst, (const uint4*)P.y8, 16, chunk, slot, acc);
    if (slot == 0) {
        float inv = 1.0f / (float)(cnt > 1 ? cnt : 1);
        float4* op = (float4*)&P.out[(size_t)node * 256 + chunk * 16];
#pragma unroll
        for (int g = 0; g < 4; ++g) {
            float4 v = op[g];
            v.x += acc[g * 4 + 0] * inv;
            v.y += acc[g * 4 + 1] * inv;
            v.z += acc[g * 4 + 2] * inv;
            v.w += acc[g * 4 + 3] * inv;
            op[g] = v;
        }
    }
}

// ---------------- p0 / p1 ----------------
__global__ __launch_bounds__(256) void k_p0(MegaP P) {
    __shared__ __align__(16) char smem[40336];
    int vb = blockIdx.x, tid = threadIdx.x;
    if (vb < 128) ph_sortA(smem, vb, tid, P.src, P.tgt, P.bsorted, P.boff);
    else if (vb < 256) ph_bncvt(smem, vb - 128, tid, P.x, P.colpart, P.xcat, P.x8);
    else ph_w2(vb - 256, tid, P.Wl2, P.Wr2, P.Wsr, P.wcat2);
}

__global__ __launch_bounds__(256) void k_p1(MegaP P) {
    __shared__ __align__(16) char smem[42496];
    int vb = blockIdx.x, tid = threadIdx.x;
    if (vb < 79) ph_sortB(smem, vb, tid, P.bsorted, P.boff, P.csr, P.nodecnt);
    else if (vb < 335) ph_w1(smem, vb - 79, tid, P.colpart, P.gamma, P.Wl1, P.Wr1, P.wcat1);
    else ph_bias(smem, tid, P.colpart, P.gamma, P.beta, P.Wl1, P.Wr1, P.bl1, P.bl2, P.bs,
                 P.bias1, P.biasc);
}

// ---- fused GEMM: h1 = relu([x|agg1]@wcat1^T+b1); y8 = fp8(h1@Wl2^T);
//      out = h1@Wr2^T + x@Ws^T + biasc      (BM=64, BN=256, 4 waves) ----
__global__ __launch_bounds__(256) void k_mm(MegaP P) {
    __shared__ __align__(16) char smem[73728];
    ushort* As = (ushort*)smem;             // 64 x 64   = 8 KB
    ushort* Bs = (ushort*)(smem + 8192);    // 256 x 64  = 32 KB
    ushort* H1 = (ushort*)(smem + 40960);   // 64 x 256  = 32 KB (swizzled)
    const int tid = threadIdx.x;
    const int wid = tid >> 6;
    const int lane = tid & 63;
    const int m0 = blockIdx.x * 64;
    const int n0 = wid * 64;
    const int srow = lane >> 3;
    const int schunk = (lane & 7) ^ srow;
    const int fr = lane & 15;
    const int kg = lane >> 4;
    const int swz = (fr & 7) * 8;
    const int kgo = kg * 8;

    f32x4 acc[4][4];
#pragma unroll
    for (int i = 0; i < 4; ++i)
#pragma unroll
        for (int j = 0; j < 4; ++j) acc[i][j] = (f32x4){0.f, 0.f, 0.f, 0.f};

    // ---- phase 1: h1 = [x|agg1] @ wcat1^T  (K=256) ----
#pragma unroll
    for (int kt = 0; kt < 4; ++kt) {
#pragma unroll
        for (int i = 0; i < 2; ++i) {
            int rb = i * 32 + wid * 8;
            gload16(&P.xcat[(size_t)(m0 + rb + srow) * 256 + kt * 64 + schunk * 8], &As[rb * 64]);
        }
#pragma unroll
        for (int i = 0; i < 8; ++i) {
            int rb = i * 32 + wid * 8;
            gload16(&P.wcat1[(size_t)(rb + srow) * 256 + kt * 64 + schunk * 8], &Bs[rb * 64]);
        }
        __syncthreads();
#pragma unroll
        for (int ks = 0; ks < 2; ++ks) {
            bf16x8 a[4], b[4];
            int koff = ks * 32 + kgo;
#pragma unroll
            for (int f = 0; f < 4; ++f) {
                a[f] = *(const bf16x8*)&As[(f * 16 + fr) * 64 + (koff ^ swz)];
                b[f] = *(const bf16x8*)&Bs[(n0 + f * 16 + fr) * 64 + (koff ^ swz)];
            }
#pragma unroll
            for (int i = 0; i < 4; ++i)
#pragma unroll
                for (int j = 0; j < 4; ++j)
                    acc[i][j] = __builtin_amdgcn_mfma_f32_16x16x32_bf16(a[i], b[j], acc[i][j], 0, 0, 0);
        }
        __syncthreads();
    }
    // epilogue 1: relu + bias -> swizzled H1
#pragma unroll
    for (int j = 0; j < 4; ++j) {
        int n = n0 + j * 16 + fr;
        float bv = P.bias1[n];
#pragma unroll
        for (int i = 0; i < 4; ++i)
#pragma unroll
            for (int r = 0; r < 4; ++r) {
                int row = i * 16 + kg * 4 + r;
                float v = fmaxf(acc[i][j][r] + bv, 0.f);
                H1[h1addr(row, n)] = f2bf(v);
            }
    }
    __syncthreads();

    // ---- phase 2a: Y2 = h1 @ Wl2^T -> y8 ----
#pragma unroll
    for (int i = 0; i < 4; ++i)
#pragma unroll
        for (int j = 0; j < 4; ++j) acc[i][j] = (f32x4){0.f, 0.f, 0.f, 0.f};
#pragma unroll
    for (int kt = 0; kt < 4; ++kt) {
#pragma unroll
        for (int i = 0; i < 8; ++i) {
            int rb = i * 32 + wid * 8;
            gload16(&P.wcat2[(size_t)(rb + srow) * 640 + 256 + kt * 64 + schunk * 8], &Bs[rb * 64]);
        }
        __syncthreads();
#pragma unroll
        for (int ks = 0; ks < 2; ++ks) {
            bf16x8 a[4], b[4];
            int koff = ks * 32 + kgo;
#pragma unroll
            for (int f = 0; f < 4; ++f) {
                a[f] = *(const bf16x8*)&H1[(f * 16 + fr) * 256 + kt * 64 + (koff ^ swz)];
                b[f] = *(const bf16x8*)&Bs[(n0 + f * 16 + fr) * 64 + (koff ^ swz)];
            }
#pragma unroll
            for (int i = 0; i < 4; ++i)
#pragma unroll
                for (int j = 0; j < 4; ++j)
                    acc[i][j] = __builtin_amdgcn_mfma_f32_16x16x32_bf16(a[i], b[j], acc[i][j], 0, 0, 0);
        }
        __syncthreads();
    }
#pragma unroll
    for (int j = 0; j < 4; ++j) {
        int n = n0 + j * 16 + fr;
#pragma unroll
        for (int i = 0; i < 4; ++i)
#pragma unroll
            for (int r = 0; r < 4; ++r) {
                int m = m0 + i * 16 + kg * 4 + r;
                if (m < NN) P.y8[(size_t)m * 256 + n] = fp81(acc[i][j][r]);
            }
    }

    // ---- phase 2b: out = h1 @ Wr2^T + x @ Ws^T + biasc ----
#pragma unroll
    for (int i = 0; i < 4; ++i)
#pragma unroll
        for (int j = 0; j < 4; ++j) acc[i][j] = (f32x4){0.f, 0.f, 0.f, 0.f};
#pragma unroll
    for (int kt = 0; kt < 4; ++kt) {
#pragma unroll
        for (int i = 0; i < 8; ++i) {
            int rb = i * 32 + wid * 8;
            gload16(&P.wcat2[(size_t)(rb + srow) * 640 + kt * 64 + schunk * 8], &Bs[rb * 64]);
        }
        __syncthreads();
#pragma unroll
        for (int ks = 0; ks < 2; ++ks) {
            bf16x8 a[4], b[4];
            int koff = ks * 32 + kgo;
#pragma unroll
            for (int f = 0; f < 4; ++f) {
                a[f] = *(const bf16x8*)&H1[(f * 16 + fr) * 256 + kt * 64 + (koff ^ swz)];
                b[f] = *(const bf16x8*)&Bs[(n0 + f * 16 + fr) * 64 + (koff ^ swz)];
            }
#pragma unroll
            for (int i = 0; i < 4; ++i)
#pragma unroll
                for (int j = 0; j < 4; ++j)
                    acc[i][j] = __builtin_amdgcn_mfma_f32_16x16x32_bf16(a[i], b[j], acc[i][j], 0, 0, 0);
        }
        __syncthreads();
    }
    // + x @ Ws^T (K=128; x = xcat cols 0:128)
#pragma unroll
    for (int kt = 0; kt < 2; ++kt) {
#pragma unroll
        for (int i = 0; i < 2; ++i) {
            int rb = i * 32 + wid * 8;
            gload16(&P.xcat[(size_t)(m0 + rb + srow) * 256 + kt * 64 + schunk * 8], &As[rb * 64]);
        }
#pragma unroll
        for (int i = 0; i < 8; ++i) {
            int rb = i * 32 + wid * 8;
            gload16(&P.wcat2[(size_t)(rb + srow) * 640 + 512 + kt * 64 + schunk * 8], &Bs[rb * 64]);
        }
        __syncthreads();
#pragma unroll
        for (int ks = 0; ks < 2; ++ks) {
            bf16x8 a[4], b[4];
            int koff = ks * 32 + kgo;
#pragma unroll
            for (int f = 0; f < 4; ++f) {
                a[f] = *(const bf16x8*)&As[(f * 16 + fr) * 64 + (koff ^ swz)];
                b[f] = *(const bf16x8*)&Bs[(n0 + f * 16 + fr) * 64 + (koff ^ swz)];
            }
#pragma unroll
            for (int i = 0; i < 4; ++i)
#pragma unroll
                for (int j = 0; j < 4; ++j)
                    acc[i][j] = __builtin_amdgcn_mfma_f32_16x16x32_bf16(a[i], b[j], acc[i][j], 0, 0, 0);
        }
        __syncthreads();
    }
#pragma unroll
    for (int j = 0; j < 4; ++j) {
        int n = n0 + j * 16 + fr;
        float bv = P.biasc[n];
#pragma unroll
        for (int i = 0; i < 4; ++i)
#pragma unroll
            for (int r = 0; r < 4; ++r) {
                int m = m0 + i * 16 + kg * 4 + r;
                if (m < NN) P.out[(size_t)m * 256 + n] = acc[i][j][r] + bv;
            }
    }
}

extern "C" void kernel_launch(void* const* d_in, const int* in_sizes, int n_in,
                              void* d_out, int out_size, void* d_ws, size_t ws_size,
                              hipStream_t stream) {
    const float* x  = (const float*)d_in[0];
    const int*   ei = (const int*)d_in[1];

    char* base = (char*)d_ws;
    size_t off = 0;
    auto alloc = [&](size_t bytes) -> void* {
        void* p = base + off;
        off += (bytes + 255) & ~(size_t)255;
        return p;
    };

    MegaP P;
    P.x = x; P.src = ei; P.tgt = ei + NE;
    P.gamma = (const float*)d_in[2];
    P.beta  = (const float*)d_in[3];
    P.Wl1   = (const float*)d_in[4];
    P.bl1   = (const float*)d_in[5];
    P.Wr1   = (const float*)d_in[6];
    P.Wl2   = (const float*)d_in[7];
    P.bl2   = (const float*)d_in[8];
    P.Wr2   = (const float*)d_in[9];
    P.Wsr   = (const float*)d_in[10];
    P.bs    = (const float*)d_in[11];
    P.out   = (float*)d_out;

    P.colpart = (float*)alloc(128 * 256 * sizeof(float));
    P.bias1   = (float*)alloc(DOUT * sizeof(float));
    P.biasc   = (float*)alloc(DOUT * sizeof(float));
    P.nodecnt = (int*)alloc(NN * sizeof(int));
    P.boff    = (int*)alloc((size_t)NSB * (NBKT + 1) * sizeof(int));
    P.bsorted = (uint*)alloc((size_t)NE * sizeof(uint));
    P.csr     = (ushort*)alloc((size_t)MPAD * SLOTS_PN * sizeof(ushort));
    P.xcat    = (ushort*)alloc((size_t)MPAD * 256 * sizeof(ushort));   // [x | agg1]
    P.wcat1   = (ushort*)alloc(256 * 256 * sizeof(ushort));
    P.wcat2   = (ushort*)alloc(256 * 640 * sizeof(ushort));
    P.x8      = (uint*)alloc((size_t)MPAD * 128);
    P.y8      = (uchar*)alloc((size_t)MPAD * 256);

    k_p0<<<P0_N, 256, 0, stream>>>(P);
    k_p1<<<P1_N, 256, 0, stream>>>(P);
    k_agg1<<<NN / 4, 256, 0, stream>>>(P);
    k_mm<<<MPAD / 64, 256, 0, stream>>>(P);
    k_agg2o<<<NN / 4, 256, 0, stream>>>(P);
}